// Round 3
// baseline (342.325 us; speedup 1.0000x reference)
//
#include <hip/hip_runtime.h>
#include <math.h>

#define EPS 1e-5f
#define ROWS 4096  // B*N

typedef __attribute__((ext_vector_type(8))) short short8;
typedef __attribute__((ext_vector_type(4))) float floatx4;

__device__ inline short f2bf(float f) {
    unsigned u = __builtin_bit_cast(unsigned, f);
    unsigned r = (u + 0x7fffu + ((u >> 16) & 1u)) >> 16;
    return (short)r;
}

// ---------------------------------------------------------------------------
// Fused LayerNorm + bf16 convert. grid (1024, T): block = 256 thr = 4 rows.
// ---------------------------------------------------------------------------
__global__ __launch_bounds__(256) void lnconv(
    const float* __restrict__ x0, const float* __restrict__ x1,
    const float* __restrict__ x2, const float* __restrict__ g,
    const float* __restrict__ bb, short* __restrict__ out) {
    int tensor = blockIdx.y;
    const float* x = tensor == 0 ? x0 : (tensor == 1 ? x1 : x2);
    int t = threadIdx.x;
    int row = blockIdx.x * 4 + (t >> 6);
    int col = (t & 63) * 8;
    const float* xr = x + (size_t)row * 512 + col;
    float4 v0 = *(const float4*)xr;
    float4 v1 = *(const float4*)(xr + 4);
    float s = v0.x + v0.y + v0.z + v0.w + v1.x + v1.y + v1.z + v1.w;
    float sq = v0.x * v0.x + v0.y * v0.y + v0.z * v0.z + v0.w * v0.w +
               v1.x * v1.x + v1.y * v1.y + v1.z * v1.z + v1.w * v1.w;
#pragma unroll
    for (int off = 32; off; off >>= 1) {
        s += __shfl_xor(s, off);
        sq += __shfl_xor(sq, off);
    }
    float m = s * (1.f / 512.f);
    float rstd = rsqrtf(sq * (1.f / 512.f) - m * m + EPS);
    float4 g0 = *(const float4*)(g + col);
    float4 g1 = *(const float4*)(g + col + 4);
    float4 b0 = *(const float4*)(bb + col);
    float4 b1 = *(const float4*)(bb + col + 4);
    short8 o;
    o[0] = f2bf((v0.x - m) * rstd * g0.x + b0.x);
    o[1] = f2bf((v0.y - m) * rstd * g0.y + b0.y);
    o[2] = f2bf((v0.z - m) * rstd * g0.z + b0.z);
    o[3] = f2bf((v0.w - m) * rstd * g0.w + b0.w);
    o[4] = f2bf((v1.x - m) * rstd * g1.x + b1.x);
    o[5] = f2bf((v1.y - m) * rstd * g1.y + b1.y);
    o[6] = f2bf((v1.z - m) * rstd * g1.z + b1.z);
    o[7] = f2bf((v1.w - m) * rstd * g1.w + b1.w);
    *(short8*)(out + (size_t)(tensor * 4096 + row) * 512 + col) = o;
}

// ---------------------------------------------------------------------------
__global__ void wconv(const float* __restrict__ w0, const float* __restrict__ w1,
                      const float* __restrict__ w2, const float* __restrict__ w3,
                      short* __restrict__ o0, short* __restrict__ o1,
                      short* __restrict__ o2, short* __restrict__ o3) {
    int y = blockIdx.y;
    const float* src = y == 0 ? w0 : (y == 1 ? w1 : (y == 2 ? w2 : w3));
    short* dst = y == 0 ? o0 : (y == 1 ? o1 : (y == 2 ? o2 : o3));
    int n = (y < 2) ? 262144 : 1048576;
    int idx = (blockIdx.x * 256 + threadIdx.x) * 8;
    if (idx < n) {
        float4 v0 = *(const float4*)(src + idx);
        float4 v1 = *(const float4*)(src + idx + 4);
        short8 o;
        o[0] = f2bf(v0.x); o[1] = f2bf(v0.y); o[2] = f2bf(v0.z); o[3] = f2bf(v0.w);
        o[4] = f2bf(v1.x); o[5] = f2bf(v1.y); o[6] = f2bf(v1.z); o[7] = f2bf(v1.w);
        *(short8*)(dst + idx) = o;
    }
}

// ---------------------------------------------------------------------------
// bf16 MFMA NT GEMM: C[M,N] = A[M,K] @ B[N,K]^T.  Tile TM x TN, 2x2 waves,
// 16x16x32 MFMA, BK=32, global_load_lds width-16 staging.
// EPI: 0 plain, 2 +bias+resid, 3 gelu(x+bias).  OUT_BF16 selects C dtype.
// ---------------------------------------------------------------------------
template <int TM, int TN, int EPI, bool OUT_BF16>
__global__ __launch_bounds__(256) void mfma_gemm_nt(
    const short* __restrict__ A, const short* __restrict__ B,
    void* __restrict__ C, int M, int N, int K,
    const float* __restrict__ bias, const float* __restrict__ resid) {
    constexpr int FI = TM / 32;  // frags per wave along M (wave tile TM/2)
    constexpr int FJ = TN / 32;
    __shared__ short As[TM * 32];
    __shared__ short Bs[TN * 32];
    int t = threadIdx.x;
    int m0 = blockIdx.y * TM, n0 = blockIdx.x * TN;
    int w = t >> 6, lane = t & 63;
    int wm = (w & 1) * (TM / 2), wn = (w >> 1) * (TN / 2);
    floatx4 acc[FI][FJ];
#pragma unroll
    for (int i = 0; i < FI; ++i)
#pragma unroll
        for (int j = 0; j < FJ; ++j) acc[i][j] = (floatx4){0.f, 0.f, 0.f, 0.f};

    int arow = t >> 2, acol = (t & 3) * 8;
    const short* Ag = A + (size_t)(m0 + arow) * K + acol;
    const short* Bg = B + (size_t)(n0 + arow) * K + acol;
    int ldsbase = w * 1024;  // bytes, wave-uniform

    for (int k0 = 0; k0 < K; k0 += 32) {
        __syncthreads();
#pragma unroll
        for (int u = 0; u < TM / 64; ++u)
            __builtin_amdgcn_global_load_lds(
                (const __attribute__((address_space(1))) void*)(Ag + (size_t)u * 64 * K + k0),
                (__attribute__((address_space(3))) void*)((char*)As + u * 4096 + ldsbase),
                16, 0, 0);
#pragma unroll
        for (int u = 0; u < TN / 64; ++u)
            __builtin_amdgcn_global_load_lds(
                (const __attribute__((address_space(1))) void*)(Bg + (size_t)u * 64 * K + k0),
                (__attribute__((address_space(3))) void*)((char*)Bs + u * 4096 + ldsbase),
                16, 0, 0);
        __syncthreads();
        int krow = (lane >> 4) * 8;
        short8 af[FI], bf[FJ];
#pragma unroll
        for (int i = 0; i < FI; ++i)
            af[i] = *(const short8*)&As[(wm + i * 16 + (lane & 15)) * 32 + krow];
#pragma unroll
        for (int j = 0; j < FJ; ++j)
            bf[j] = *(const short8*)&Bs[(wn + j * 16 + (lane & 15)) * 32 + krow];
#pragma unroll
        for (int i = 0; i < FI; ++i)
#pragma unroll
            for (int j = 0; j < FJ; ++j)
                acc[i][j] = __builtin_amdgcn_mfma_f32_16x16x32_bf16(
                    af[i], bf[j], acc[i][j], 0, 0, 0);
    }

    int col = lane & 15, rbase = (lane >> 4) * 4;
#pragma unroll
    for (int i = 0; i < FI; ++i) {
#pragma unroll
        for (int j = 0; j < FJ; ++j) {
            int gcol = n0 + wn + j * 16 + col;
#pragma unroll
            for (int r = 0; r < 4; ++r) {
                int grow = m0 + wm + i * 16 + rbase + r;
                float v = acc[i][j][r];
                if (EPI == 2) v += bias[gcol] + resid[(size_t)grow * N + gcol];
                if (EPI == 3) {
                    v += bias[gcol];
                    v = 0.5f * v * (1.f + erff(v * 0.70710678118654752f));
                }
                if (OUT_BF16)
                    ((short*)C)[(size_t)grow * N + gcol] = f2bf(v);
                else
                    ((float*)C)[(size_t)grow * N + gcol] = v;
            }
        }
    }
}

// ---------------------------------------------------------------------------
// Per (head,row) stats: mean, 1/norm, var(ddof=1). grid (4096, 2) y: fq/fk.
// ---------------------------------------------------------------------------
__global__ void head_stats2(const float* __restrict__ fq, const float* __restrict__ fk,
                            float* __restrict__ S) {
    int row = blockIdx.x;
    int y = blockIdx.y;
    const float* f = y ? fk : fq;
    float* base = S + (size_t)y * 98304;
    int t = threadIdx.x;
    int h = t >> 6, lane = t & 63;
    float v = f[(size_t)row * 512 + t];
    float s = v, sq = v * v;
#pragma unroll
    for (int off = 32; off; off >>= 1) {
        s += __shfl_xor(s, off);
        sq += __shfl_xor(sq, off);
    }
    if (lane == 0) {
        float m = s * (1.f / 64.f);
        int idx = h * ROWS + row;
        base[idx] = m;
        base[32768 + idx] = rsqrtf(sq);
        base[65536 + idx] = (sq - 64.f * m * m) * (1.f / 63.f);
    }
}

__global__ void zero_k(float* __restrict__ p, int n) {
    int i = blockIdx.x * blockDim.x + threadIdx.x;
    if (i < n) p[i] = 0.f;
}

// Column means of fq/fk over 4096 rows. grid (128, 2), 512 thr, 32 rows each.
__global__ void colmean(const float* __restrict__ fq, const float* __restrict__ fk,
                        float* __restrict__ qg, float* __restrict__ kg) {
    int tensor = blockIdx.y;
    const float* f = tensor ? fk : fq;
    float* o = tensor ? kg : qg;
    int col = threadIdx.x;
    int r0 = blockIdx.x * 32;
    float s = 0.f;
    for (int r = 0; r < 32; ++r) s += f[(size_t)(r0 + r) * 512 + col];
    atomicAdd(&o[col], s * (1.f / 4096.f));
}

// Tiny policy MLP.
__global__ void policy_mlp(const float* __restrict__ qg, const float* __restrict__ kg,
                           const float* __restrict__ W1, const float* __restrict__ b1,
                           const float* __restrict__ g, const float* __restrict__ bb,
                           const float* __restrict__ W2, const float* __restrict__ b2,
                           float* __restrict__ wmix) {
    int h = blockIdx.x, j = threadIdx.x;  // 64
    float acc = 0.f;
    const float* w1r = W1 + j * 128;
    for (int i = 0; i < 64; ++i) acc += qg[h * 64 + i] * w1r[i];
    for (int i = 0; i < 64; ++i) acc += kg[h * 64 + i] * w1r[64 + i];
    acc += b1[j];
    float s = acc, sq = acc * acc;
#pragma unroll
    for (int off = 32; off; off >>= 1) {
        s += __shfl_xor(s, off);
        sq += __shfl_xor(sq, off);
    }
    float m = s * (1.f / 64.f);
    float var = sq * (1.f / 64.f) - m * m;
    float xh = (acc - m) * rsqrtf(var + EPS) * g[j] + bb[j];
    float r = fmaxf(xh, 0.f);
    float l[3];
#pragma unroll
    for (int c = 0; c < 3; ++c) {
        float p = r * W2[c * 64 + j];
#pragma unroll
        for (int off = 32; off; off >>= 1) p += __shfl_xor(p, off);
        l[c] = p + b2[c];
    }
    if (j == 0) {
        float mx = fmaxf(l[0], fmaxf(l[1], l[2]));
        float e0 = expf(l[0] - mx), e1 = expf(l[1] - mx), e2 = expf(l[2] - mx);
        float inv = 1.f / (e0 + e1 + e2);
        wmix[h * 3 + 0] = e0 * inv;
        wmix[h * 3 + 1] = e1 * inv;
        wmix[h * 3 + 2] = e2 * inv;
    }
}

// ---------------------------------------------------------------------------
// K-side partial reduction per (h,b,chunk of 64 rows): atomicAdd into Mbuf.
// Mbuf per hb: [m1 4096][m2 4096][skv 64][smk 64]. grid (32, 16).
// ---------------------------------------------------------------------------
__global__ __launch_bounds__(256) void ksideP(
    const float* __restrict__ fk, const float* __restrict__ fv,
    const float* __restrict__ rnk, const float* __restrict__ kvv,
    const float* __restrict__ mk, float* __restrict__ Mbuf) {
    int hb = blockIdx.x;
    int chunk = blockIdx.y;
    int h = hb >> 2, b = hb & 3;
    __shared__ float fkt[2048], fvt[2048];
    __shared__ float rs[32], kvs[32], mks[32];
    int t = threadIdx.x;
    int td = t >> 4, te = t & 15;
    float m1[4][4] = {}, m2[4][4] = {};
    float skv = 0.f, smk = 0.f;
    int mstart = chunk * 64;
    for (int m0 = mstart; m0 < mstart + 64; m0 += 32) {
        __syncthreads();
#pragma unroll
        for (int u = 0; u < 2; ++u) {
            int idx = u * 1024 + t * 4;
            int mm = idx >> 6, d = idx & 63;
            size_t grow = (size_t)(b * 1024 + m0 + mm) * 512 + h * 64 + d;
            *(float4*)&fkt[idx] = *(const float4*)&fk[grow];
            *(float4*)&fvt[idx] = *(const float4*)&fv[grow];
        }
        if (t < 32) {
            int sidx = h * ROWS + b * 1024 + m0 + t;
            rs[t] = rnk[sidx];
            kvs[t] = kvv[sidx];
            mks[t] = mk[sidx];
        }
        __syncthreads();
        for (int mi = 0; mi < 32; ++mi) {
            float r = rs[mi];
            float4 kq = *(const float4*)&fkt[mi * 64 + td * 4];
            float4 vq = *(const float4*)&fvt[mi * 64 + te * 4];
            float kr[4] = {kq.x, kq.y, kq.z, kq.w};
            float vr[4] = {vq.x, vq.y, vq.z, vq.w};
#pragma unroll
            for (int i = 0; i < 4; ++i) {
                float kv_ = kr[i], krr = kv_ * r;
#pragma unroll
                for (int j = 0; j < 4; ++j) {
                    m2[i][j] += kv_ * vr[j];
                    m1[i][j] += krr * vr[j];
                }
            }
            if (t < 64) {
                skv += kvs[mi] * fvt[mi * 64 + t];
                smk += mks[mi] * fvt[mi * 64 + t];
            }
        }
    }
    float* base = Mbuf + (size_t)hb * 8320;
#pragma unroll
    for (int i = 0; i < 4; ++i)
#pragma unroll
        for (int j = 0; j < 4; ++j) {
            atomicAdd(&base[(td * 4 + i) * 64 + te * 4 + j], m1[i][j]);
            atomicAdd(&base[4096 + (td * 4 + i) * 64 + te * 4 + j], m2[i][j]);
        }
    if (t < 64) {
        atomicAdd(&base[8192 + t], skv);
        atomicAdd(&base[8256 + t], smk);
    }
}

// ---------------------------------------------------------------------------
// Q-side apply, 64 rows per block. grid (16, 32). Writes attn in bf16.
// ---------------------------------------------------------------------------
__global__ __launch_bounds__(256) void qside(
    const float* __restrict__ fq, const float* __restrict__ Mbuf,
    const float* __restrict__ rnq, const float* __restrict__ mq,
    const float* __restrict__ qv, const float* __restrict__ wmix,
    short* __restrict__ attn_out) {
    int ntile = blockIdx.x, hb = blockIdx.y;
    int h = hb >> 2, b = hb & 3;
    __shared__ float M1s[4096], M2s[4096], fqt[4096];
    __shared__ float Skvs[64], Smks[64], rnqs[64], mqs[64], qvs[64];
    int t = threadIdx.x;
    const float* base = Mbuf + (size_t)hb * 8320;
#pragma unroll
    for (int u = 0; u < 4; ++u) {
        int idx = t * 4 + u * 1024;
        *(float4*)&M1s[idx] = *(const float4*)&base[idx];
        *(float4*)&M2s[idx] = *(const float4*)&base[4096 + idx];
    }
    int n0 = ntile * 64;
#pragma unroll
    for (int u = 0; u < 4; ++u) {
        int idx = t * 4 + u * 1024;
        int r = idx >> 6, d = idx & 63;
        *(float4*)&fqt[idx] = *(const float4*)&fq[(size_t)(b * 1024 + n0 + r) * 512 + h * 64 + d];
    }
    if (t < 64) {
        Skvs[t] = base[8192 + t];
        Smks[t] = base[8256 + t];
        int sidx = h * ROWS + b * 1024 + n0 + t;
        rnqs[t] = rnq[sidx];
        mqs[t] = mq[sidx];
        qvs[t] = qv[sidx];
    }
    __syncthreads();
    float cw = wmix[h * 3 + 0], covw = wmix[h * 3 + 1], vw = wmix[h * 3 + 2];
    int e = t & 63, rq = t >> 6;
    float a1[16] = {}, a2[16] = {};
    for (int d4 = 0; d4 < 64; d4 += 4) {
        float md1[4], md2[4];
#pragma unroll
        for (int dd = 0; dd < 4; ++dd) {
            md1[dd] = M1s[(d4 + dd) * 64 + e];
            md2[dd] = M2s[(d4 + dd) * 64 + e];
        }
#pragma unroll
        for (int i = 0; i < 16; ++i) {
            float4 f = *(const float4*)&fqt[(rq * 16 + i) * 64 + d4];
            a1[i] += f.x * md1[0] + f.y * md1[1] + f.z * md1[2] + f.w * md1[3];
            a2[i] += f.x * md2[0] + f.y * md2[1] + f.z * md2[2] + f.w * md2[3];
        }
    }
    float c2 = covw * (1.f / 64.f), c3 = vw * (1.f / 64.f);
#pragma unroll
    for (int i = 0; i < 16; ++i) {
        int rr = rq * 16 + i;
        float v = cw * rnqs[rr] * a1[i] + c2 * a2[i] + c3 * qvs[rr] * Skvs[e] -
                  covw * mqs[rr] * Smks[e];
        attn_out[(size_t)(b * 1024 + n0 + rr) * 512 + h * 64 + e] = f2bf(v);
    }
}

// ---------------------------------------------------------------------------
extern "C" void kernel_launch(void* const* d_in, const int* in_sizes, int n_in,
                              void* d_out, int out_size, void* d_ws, size_t ws_size,
                              hipStream_t stream) {
    const float* q = (const float*)d_in[0];
    const float* k = (const float*)d_in[1];
    const float* v = (const float*)d_in[2];
    const float* Win = (const float*)d_in[3];
    const float* Wout = (const float*)d_in[4];
    const float* bout = (const float*)d_in[5];
    const float* g1 = (const float*)d_in[6];
    const float* b1n = (const float*)d_in[7];
    const float* g2 = (const float*)d_in[8];
    const float* b2n = (const float*)d_in[9];
    const float* Wup = (const float*)d_in[10];
    const float* bup = (const float*)d_in[11];
    const float* Wdn = (const float*)d_in[12];
    const float* bdn = (const float*)d_in[13];
    const float* wpW1 = (const float*)d_in[14];
    const float* wpb1 = (const float*)d_in[15];
    const float* wpg = (const float*)d_in[16];
    const float* wpb = (const float*)d_in[17];
    const float* wpW2 = (const float*)d_in[18];
    const float* wpb2 = (const float*)d_in[19];
    float* out = (float*)d_out;

    float* wsf = (float*)d_ws;
    float* fq = wsf;
    float* fk = wsf + 2097152;
    float* fv = wsf + 2 * 2097152;
    short* hmid = (short*)wsf;  // 4096x2048 bf16, reuses fq/fk region later
    short* qkvln = (short*)(wsf + 6291456);
    short* attnbf = (short*)(wsf + 6291456);
    short* x2bf = (short*)(wsf + 6291456 + 1048576);
    short* Winbf = (short*)(wsf + 9437184);
    short* Woutbf = (short*)(wsf + 9437184 + 131072);
    short* Wupbf = (short*)(wsf + 9437184 + 262144);
    short* Wdnbf = (short*)(wsf + 9437184 + 262144 + 524288);
    float* S = wsf + 10747904;       // [2][3][32768] head stats
    float* qg = S + 196608;          // 512
    float* kg = qg + 512;            // 512
    float* Mbuf = kg + 512;          // 32*8320 (zeroed, atomics)
    float* wmix = Mbuf + 266240;     // 32
    float* mqS = S, *rnqS = S + 32768, *qvS = S + 65536;
    float* mkS = S + 98304, *rnkS = S + 131072, *kvS = S + 163840;

    // 1. weights -> bf16 ; LN(q/k/v) -> stacked bf16 ; zero qg/kg/Mbuf
    wconv<<<dim3(512, 4), 256, 0, stream>>>(Win, Wout, Wup, Wdn,
                                            Winbf, Woutbf, Wupbf, Wdnbf);
    lnconv<<<dim3(1024, 3), 256, 0, stream>>>(q, k, v, g1, b1n, qkvln);
    zero_k<<<1044, 256, 0, stream>>>(qg, 267264);

    // 2. stacked projection: fqkv = LN(qkv) @ Win^T  (M=12288)
    mfma_gemm_nt<64, 128, 0, false><<<dim3(4, 192), 256, 0, stream>>>(
        qkvln, Winbf, fq, 12288, 512, 512, nullptr, nullptr);

    // 3. per-(head,row) stats + per-head global means + policy MLP
    head_stats2<<<dim3(4096, 2), 512, 0, stream>>>(fq, fk, S);
    colmean<<<dim3(128, 2), 512, 0, stream>>>(fq, fk, qg, kg);
    policy_mlp<<<8, 64, 0, stream>>>(qg, kg, wpW1, wpb1, wpg, wpb, wpW2, wpb2, wmix);

    // 4. linear-attention K-side reduction (atomic split-16) + Q-side apply
    ksideP<<<dim3(32, 16), 256, 0, stream>>>(fk, fv, rnkS, kvS, mkS, Mbuf);
    qside<<<dim3(16, 32), 256, 0, stream>>>(fq, Mbuf, rnqS, mqS, qvS, wmix, attnbf);

    // 5. q2 = q + attn @ Wout^T + bout  -> d_out
    mfma_gemm_nt<64, 64, 2, false><<<dim3(8, 64), 256, 0, stream>>>(
        attnbf, Woutbf, out, 4096, 512, 512, bout, q);

    // 6. MLP: x2 = LN(q2); h = gelu(x2@Wup^T+bup); out = q2 + h@Wdn^T + bdn
    lnconv<<<dim3(1024, 1), 256, 0, stream>>>(out, out, out, g2, b2n, x2bf);
    mfma_gemm_nt<64, 128, 3, true><<<dim3(16, 64), 256, 0, stream>>>(
        x2bf, Wupbf, hmid, 4096, 2048, 512, bup, nullptr);
    mfma_gemm_nt<64, 128, 2, false><<<dim3(4, 64), 256, 0, stream>>>(
        hmid, Wdnbf, out, 4096, 512, 2048, bdn, out);
}

// Round 4
// 271.440 us; speedup vs baseline: 1.2611x; 1.2611x over previous
//
#include <hip/hip_runtime.h>
#include <math.h>

#define EPS 1e-5f
#define ROWS 4096  // B*N

typedef __attribute__((ext_vector_type(8))) short short8;
typedef __attribute__((ext_vector_type(4))) float floatx4;

__device__ inline short f2bf(float f) {
    unsigned u = __builtin_bit_cast(unsigned, f);
    unsigned r = (u + 0x7fffu + ((u >> 16) & 1u)) >> 16;
    return (short)r;
}

// ---------------------------------------------------------------------------
// Fused LayerNorm + bf16 convert. grid (1024, T): block = 256 thr = 4 rows.
// ---------------------------------------------------------------------------
__global__ __launch_bounds__(256) void lnconv(
    const float* __restrict__ x0, const float* __restrict__ x1,
    const float* __restrict__ x2, const float* __restrict__ g,
    const float* __restrict__ bb, short* __restrict__ out) {
    int tensor = blockIdx.y;
    const float* x = tensor == 0 ? x0 : (tensor == 1 ? x1 : x2);
    int t = threadIdx.x;
    int row = blockIdx.x * 4 + (t >> 6);
    int col = (t & 63) * 8;
    const float* xr = x + (size_t)row * 512 + col;
    float4 v0 = *(const float4*)xr;
    float4 v1 = *(const float4*)(xr + 4);
    float s = v0.x + v0.y + v0.z + v0.w + v1.x + v1.y + v1.z + v1.w;
    float sq = v0.x * v0.x + v0.y * v0.y + v0.z * v0.z + v0.w * v0.w +
               v1.x * v1.x + v1.y * v1.y + v1.z * v1.z + v1.w * v1.w;
#pragma unroll
    for (int off = 32; off; off >>= 1) {
        s += __shfl_xor(s, off);
        sq += __shfl_xor(sq, off);
    }
    float m = s * (1.f / 512.f);
    float rstd = rsqrtf(sq * (1.f / 512.f) - m * m + EPS);
    float4 g0 = *(const float4*)(g + col);
    float4 g1 = *(const float4*)(g + col + 4);
    float4 b0 = *(const float4*)(bb + col);
    float4 b1 = *(const float4*)(bb + col + 4);
    short8 o;
    o[0] = f2bf((v0.x - m) * rstd * g0.x + b0.x);
    o[1] = f2bf((v0.y - m) * rstd * g0.y + b0.y);
    o[2] = f2bf((v0.z - m) * rstd * g0.z + b0.z);
    o[3] = f2bf((v0.w - m) * rstd * g0.w + b0.w);
    o[4] = f2bf((v1.x - m) * rstd * g1.x + b1.x);
    o[5] = f2bf((v1.y - m) * rstd * g1.y + b1.y);
    o[6] = f2bf((v1.z - m) * rstd * g1.z + b1.z);
    o[7] = f2bf((v1.w - m) * rstd * g1.w + b1.w);
    *(short8*)(out + (size_t)(tensor * 4096 + row) * 512 + col) = o;
}

// ---------------------------------------------------------------------------
__global__ void wconv(const float* __restrict__ w0, const float* __restrict__ w1,
                      const float* __restrict__ w2, const float* __restrict__ w3,
                      short* __restrict__ o0, short* __restrict__ o1,
                      short* __restrict__ o2, short* __restrict__ o3) {
    int y = blockIdx.y;
    const float* src = y == 0 ? w0 : (y == 1 ? w1 : (y == 2 ? w2 : w3));
    short* dst = y == 0 ? o0 : (y == 1 ? o1 : (y == 2 ? o2 : o3));
    int n = (y < 2) ? 262144 : 1048576;
    int idx = (blockIdx.x * 256 + threadIdx.x) * 8;
    if (idx < n) {
        float4 v0 = *(const float4*)(src + idx);
        float4 v1 = *(const float4*)(src + idx + 4);
        short8 o;
        o[0] = f2bf(v0.x); o[1] = f2bf(v0.y); o[2] = f2bf(v0.z); o[3] = f2bf(v0.w);
        o[4] = f2bf(v1.x); o[5] = f2bf(v1.y); o[6] = f2bf(v1.z); o[7] = f2bf(v1.w);
        *(short8*)(dst + idx) = o;
    }
}

// ---------------------------------------------------------------------------
// bf16 MFMA NT GEMM: C[M,N] = A[M,K] @ B[N,K]^T.  Tile TM x TN, 2x2 waves,
// 16x16x32 MFMA, BK=32, global_load_lds width-16 staging.
// EPI: 0 plain, 2 +bias+resid, 3 gelu(x+bias).  OUT_BF16 selects C dtype.
// ---------------------------------------------------------------------------
template <int TM, int TN, int EPI, bool OUT_BF16>
__global__ __launch_bounds__(256) void mfma_gemm_nt(
    const short* __restrict__ A, const short* __restrict__ B,
    void* __restrict__ C, int M, int N, int K,
    const float* __restrict__ bias, const float* __restrict__ resid) {
    constexpr int FI = TM / 32;
    constexpr int FJ = TN / 32;
    __shared__ short As[TM * 32];
    __shared__ short Bs[TN * 32];
    int t = threadIdx.x;
    int m0 = blockIdx.y * TM, n0 = blockIdx.x * TN;
    int w = t >> 6, lane = t & 63;
    int wm = (w & 1) * (TM / 2), wn = (w >> 1) * (TN / 2);
    floatx4 acc[FI][FJ];
#pragma unroll
    for (int i = 0; i < FI; ++i)
#pragma unroll
        for (int j = 0; j < FJ; ++j) acc[i][j] = (floatx4){0.f, 0.f, 0.f, 0.f};

    int arow = t >> 2, acol = (t & 3) * 8;
    const short* Ag = A + (size_t)(m0 + arow) * K + acol;
    const short* Bg = B + (size_t)(n0 + arow) * K + acol;
    int ldsbase = w * 1024;  // bytes, wave-uniform

    for (int k0 = 0; k0 < K; k0 += 32) {
        __syncthreads();
#pragma unroll
        for (int u = 0; u < TM / 64; ++u)
            __builtin_amdgcn_global_load_lds(
                (const __attribute__((address_space(1))) void*)(Ag + (size_t)u * 64 * K + k0),
                (__attribute__((address_space(3))) void*)((char*)As + u * 4096 + ldsbase),
                16, 0, 0);
#pragma unroll
        for (int u = 0; u < TN / 64; ++u)
            __builtin_amdgcn_global_load_lds(
                (const __attribute__((address_space(1))) void*)(Bg + (size_t)u * 64 * K + k0),
                (__attribute__((address_space(3))) void*)((char*)Bs + u * 4096 + ldsbase),
                16, 0, 0);
        __syncthreads();
        int krow = (lane >> 4) * 8;
        short8 af[FI], bf[FJ];
#pragma unroll
        for (int i = 0; i < FI; ++i)
            af[i] = *(const short8*)&As[(wm + i * 16 + (lane & 15)) * 32 + krow];
#pragma unroll
        for (int j = 0; j < FJ; ++j)
            bf[j] = *(const short8*)&Bs[(wn + j * 16 + (lane & 15)) * 32 + krow];
#pragma unroll
        for (int i = 0; i < FI; ++i)
#pragma unroll
            for (int j = 0; j < FJ; ++j)
                acc[i][j] = __builtin_amdgcn_mfma_f32_16x16x32_bf16(
                    af[i], bf[j], acc[i][j], 0, 0, 0);
    }

    int col = lane & 15, rbase = (lane >> 4) * 4;
#pragma unroll
    for (int i = 0; i < FI; ++i) {
#pragma unroll
        for (int j = 0; j < FJ; ++j) {
            int gcol = n0 + wn + j * 16 + col;
#pragma unroll
            for (int r = 0; r < 4; ++r) {
                int grow = m0 + wm + i * 16 + rbase + r;
                float v = acc[i][j][r];
                if (EPI == 2) v += bias[gcol] + resid[(size_t)grow * N + gcol];
                if (EPI == 3) {
                    v += bias[gcol];
                    v = 0.5f * v * (1.f + erff(v * 0.70710678118654752f));
                }
                if (OUT_BF16)
                    ((short*)C)[(size_t)grow * N + gcol] = f2bf(v);
                else
                    ((float*)C)[(size_t)grow * N + gcol] = v;
            }
        }
    }
}

// ---------------------------------------------------------------------------
// Per (head,row) stats: mean, 1/norm, var(ddof=1). grid (4096, 2) y: fq/fk.
// ---------------------------------------------------------------------------
__global__ void head_stats2(const float* __restrict__ fq, const float* __restrict__ fk,
                            float* __restrict__ S) {
    int row = blockIdx.x;
    int y = blockIdx.y;
    const float* f = y ? fk : fq;
    float* base = S + (size_t)y * 98304;
    int t = threadIdx.x;
    int h = t >> 6, lane = t & 63;
    float v = f[(size_t)row * 512 + t];
    float s = v, sq = v * v;
#pragma unroll
    for (int off = 32; off; off >>= 1) {
        s += __shfl_xor(s, off);
        sq += __shfl_xor(sq, off);
    }
    if (lane == 0) {
        float m = s * (1.f / 64.f);
        int idx = h * ROWS + row;
        base[idx] = m;
        base[32768 + idx] = rsqrtf(sq);
        base[65536 + idx] = (sq - 64.f * m * m) * (1.f / 63.f);
    }
}

__global__ void zero_k(float* __restrict__ p, int n) {
    int i = blockIdx.x * blockDim.x + threadIdx.x;
    if (i < n) p[i] = 0.f;
}

// Column means of fq/fk over 4096 rows. grid (128, 2), 512 thr, 32 rows each.
__global__ void colmean(const float* __restrict__ fq, const float* __restrict__ fk,
                        float* __restrict__ qg, float* __restrict__ kg) {
    int tensor = blockIdx.y;
    const float* f = tensor ? fk : fq;
    float* o = tensor ? kg : qg;
    int col = threadIdx.x;
    int r0 = blockIdx.x * 32;
    float s = 0.f;
    for (int r = 0; r < 32; ++r) s += f[(size_t)(r0 + r) * 512 + col];
    atomicAdd(&o[col], s * (1.f / 4096.f));
}

// Tiny policy MLP.
__global__ void policy_mlp(const float* __restrict__ qg, const float* __restrict__ kg,
                           const float* __restrict__ W1, const float* __restrict__ b1,
                           const float* __restrict__ g, const float* __restrict__ bb,
                           const float* __restrict__ W2, const float* __restrict__ b2,
                           float* __restrict__ wmix) {
    int h = blockIdx.x, j = threadIdx.x;  // 64
    float acc = 0.f;
    const float* w1r = W1 + j * 128;
    for (int i = 0; i < 64; ++i) acc += qg[h * 64 + i] * w1r[i];
    for (int i = 0; i < 64; ++i) acc += kg[h * 64 + i] * w1r[64 + i];
    acc += b1[j];
    float s = acc, sq = acc * acc;
#pragma unroll
    for (int off = 32; off; off >>= 1) {
        s += __shfl_xor(s, off);
        sq += __shfl_xor(sq, off);
    }
    float m = s * (1.f / 64.f);
    float var = sq * (1.f / 64.f) - m * m;
    float xh = (acc - m) * rsqrtf(var + EPS) * g[j] + bb[j];
    float r = fmaxf(xh, 0.f);
    float l[3];
#pragma unroll
    for (int c = 0; c < 3; ++c) {
        float p = r * W2[c * 64 + j];
#pragma unroll
        for (int off = 32; off; off >>= 1) p += __shfl_xor(p, off);
        l[c] = p + b2[c];
    }
    if (j == 0) {
        float mx = fmaxf(l[0], fmaxf(l[1], l[2]));
        float e0 = expf(l[0] - mx), e1 = expf(l[1] - mx), e2 = expf(l[2] - mx);
        float inv = 1.f / (e0 + e1 + e2);
        wmix[h * 3 + 0] = e0 * inv;
        wmix[h * 3 + 1] = e1 * inv;
        wmix[h * 3 + 2] = e2 * inv;
    }
}

// ---------------------------------------------------------------------------
// K-side partial reduction per (h,b,chunk of 128 rows). grid (32, 8).
// Each block stores its own partial [m1 4096][m2 4096][skv 64][smk 64].
// ---------------------------------------------------------------------------
__global__ __launch_bounds__(256) void ksideP(
    const float* __restrict__ fk, const float* __restrict__ fv,
    const float* __restrict__ rnk, const float* __restrict__ kvv,
    const float* __restrict__ mk, float* __restrict__ Mpart) {
    int hb = blockIdx.x;
    int chunk = blockIdx.y;
    int h = hb >> 2, b = hb & 3;
    __shared__ float fkt[2048], fvt[2048];
    __shared__ float rs[32], kvs[32], mks[32];
    int t = threadIdx.x;
    int td = t >> 4, te = t & 15;
    float m1[4][4] = {}, m2[4][4] = {};
    float skv = 0.f, smk = 0.f;
    int mstart = chunk * 128;
    for (int m0 = mstart; m0 < mstart + 128; m0 += 32) {
        __syncthreads();
#pragma unroll
        for (int u = 0; u < 2; ++u) {
            int idx = u * 1024 + t * 4;
            int mm = idx >> 6, d = idx & 63;
            size_t grow = (size_t)(b * 1024 + m0 + mm) * 512 + h * 64 + d;
            *(float4*)&fkt[idx] = *(const float4*)&fk[grow];
            *(float4*)&fvt[idx] = *(const float4*)&fv[grow];
        }
        if (t < 32) {
            int sidx = h * ROWS + b * 1024 + m0 + t;
            rs[t] = rnk[sidx];
            kvs[t] = kvv[sidx];
            mks[t] = mk[sidx];
        }
        __syncthreads();
        for (int mi = 0; mi < 32; ++mi) {
            float r = rs[mi];
            float4 kq = *(const float4*)&fkt[mi * 64 + td * 4];
            float4 vq = *(const float4*)&fvt[mi * 64 + te * 4];
            float kr[4] = {kq.x, kq.y, kq.z, kq.w};
            float vr[4] = {vq.x, vq.y, vq.z, vq.w};
#pragma unroll
            for (int i = 0; i < 4; ++i) {
                float kv_ = kr[i], krr = kv_ * r;
#pragma unroll
                for (int j = 0; j < 4; ++j) {
                    m2[i][j] += kv_ * vr[j];
                    m1[i][j] += krr * vr[j];
                }
            }
            if (t < 64) {
                skv += kvs[mi] * fvt[mi * 64 + t];
                smk += mks[mi] * fvt[mi * 64 + t];
            }
        }
    }
    float* base = Mpart + (size_t)(chunk * 32 + hb) * 8320;
#pragma unroll
    for (int i = 0; i < 4; ++i)
#pragma unroll
        for (int j = 0; j < 4; ++j) {
            base[(td * 4 + i) * 64 + te * 4 + j] = m1[i][j];
            base[4096 + (td * 4 + i) * 64 + te * 4 + j] = m2[i][j];
        }
    if (t < 64) {
        base[8192 + t] = skv;
        base[8256 + t] = smk;
    }
}

// Sum the 8 chunk-partials into Mbuf. 32*8320 elements.
__global__ void reduceM(const float* __restrict__ Mpart, float* __restrict__ Mbuf) {
    int i = blockIdx.x * 256 + threadIdx.x;
    if (i < 32 * 8320) {
        float s = 0.f;
#pragma unroll
        for (int c = 0; c < 8; ++c) s += Mpart[(size_t)c * 266240 + i];
        Mbuf[i] = s;
    }
}

// ---------------------------------------------------------------------------
// Q-side apply, 64 rows per block. grid (16, 32). Writes attn in bf16.
// ---------------------------------------------------------------------------
__global__ __launch_bounds__(256) void qside(
    const float* __restrict__ fq, const float* __restrict__ Mbuf,
    const float* __restrict__ rnq, const float* __restrict__ mq,
    const float* __restrict__ qv, const float* __restrict__ wmix,
    short* __restrict__ attn_out) {
    int ntile = blockIdx.x, hb = blockIdx.y;
    int h = hb >> 2, b = hb & 3;
    __shared__ float M1s[4096], M2s[4096], fqt[4096];
    __shared__ float Skvs[64], Smks[64], rnqs[64], mqs[64], qvs[64];
    int t = threadIdx.x;
    const float* base = Mbuf + (size_t)hb * 8320;
#pragma unroll
    for (int u = 0; u < 4; ++u) {
        int idx = t * 4 + u * 1024;
        *(float4*)&M1s[idx] = *(const float4*)&base[idx];
        *(float4*)&M2s[idx] = *(const float4*)&base[4096 + idx];
    }
    int n0 = ntile * 64;
#pragma unroll
    for (int u = 0; u < 4; ++u) {
        int idx = t * 4 + u * 1024;
        int r = idx >> 6, d = idx & 63;
        *(float4*)&fqt[idx] = *(const float4*)&fq[(size_t)(b * 1024 + n0 + r) * 512 + h * 64 + d];
    }
    if (t < 64) {
        Skvs[t] = base[8192 + t];
        Smks[t] = base[8256 + t];
        int sidx = h * ROWS + b * 1024 + n0 + t;
        rnqs[t] = rnq[sidx];
        mqs[t] = mq[sidx];
        qvs[t] = qv[sidx];
    }
    __syncthreads();
    float cw = wmix[h * 3 + 0], covw = wmix[h * 3 + 1], vw = wmix[h * 3 + 2];
    int e = t & 63, rq = t >> 6;
    float a1[16] = {}, a2[16] = {};
    for (int d4 = 0; d4 < 64; d4 += 4) {
        float md1[4], md2[4];
#pragma unroll
        for (int dd = 0; dd < 4; ++dd) {
            md1[dd] = M1s[(d4 + dd) * 64 + e];
            md2[dd] = M2s[(d4 + dd) * 64 + e];
        }
#pragma unroll
        for (int i = 0; i < 16; ++i) {
            float4 f = *(const float4*)&fqt[(rq * 16 + i) * 64 + d4];
            a1[i] += f.x * md1[0] + f.y * md1[1] + f.z * md1[2] + f.w * md1[3];
            a2[i] += f.x * md2[0] + f.y * md2[1] + f.z * md2[2] + f.w * md2[3];
        }
    }
    float c2 = covw * (1.f / 64.f), c3 = vw * (1.f / 64.f);
#pragma unroll
    for (int i = 0; i < 16; ++i) {
        int rr = rq * 16 + i;
        float v = cw * rnqs[rr] * a1[i] + c2 * a2[i] + c3 * qvs[rr] * Skvs[e] -
                  covw * mqs[rr] * Smks[e];
        attn_out[(size_t)(b * 1024 + n0 + rr) * 512 + h * 64 + e] = f2bf(v);
    }
}

// ---------------------------------------------------------------------------
extern "C" void kernel_launch(void* const* d_in, const int* in_sizes, int n_in,
                              void* d_out, int out_size, void* d_ws, size_t ws_size,
                              hipStream_t stream) {
    const float* q = (const float*)d_in[0];
    const float* k = (const float*)d_in[1];
    const float* v = (const float*)d_in[2];
    const float* Win = (const float*)d_in[3];
    const float* Wout = (const float*)d_in[4];
    const float* bout = (const float*)d_in[5];
    const float* g1 = (const float*)d_in[6];
    const float* b1n = (const float*)d_in[7];
    const float* g2 = (const float*)d_in[8];
    const float* b2n = (const float*)d_in[9];
    const float* Wup = (const float*)d_in[10];
    const float* bup = (const float*)d_in[11];
    const float* Wdn = (const float*)d_in[12];
    const float* bdn = (const float*)d_in[13];
    const float* wpW1 = (const float*)d_in[14];
    const float* wpb1 = (const float*)d_in[15];
    const float* wpg = (const float*)d_in[16];
    const float* wpb = (const float*)d_in[17];
    const float* wpW2 = (const float*)d_in[18];
    const float* wpb2 = (const float*)d_in[19];
    float* out = (float*)d_out;

    float* wsf = (float*)d_ws;
    float* fq = wsf;
    float* fk = wsf + 2097152;
    float* fv = wsf + 2 * 2097152;
    short* hmid = (short*)wsf;  // 4096x2048 bf16, reuses fq/fk region later
    short* qkvln = (short*)(wsf + 6291456);   // dead after proj GEMM
    float* Mpart = wsf + 6291456;             // 8*266240 floats, lives in qkvln region
    short* attnbf = (short*)(wsf + 6291456);  // written by qside after reduceM
    short* x2bf = (short*)(wsf + 6291456 + 1048576);
    short* Winbf = (short*)(wsf + 9437184);
    short* Woutbf = (short*)(wsf + 9437184 + 131072);
    short* Wupbf = (short*)(wsf + 9437184 + 262144);
    short* Wdnbf = (short*)(wsf + 9437184 + 262144 + 524288);
    float* S = wsf + 10747904;       // [2][3][32768] head stats
    float* qg = S + 196608;          // 512
    float* kg = qg + 512;            // 512
    float* Mbuf = kg + 512;          // 32*8320
    float* wmix = Mbuf + 266240;     // 32
    float* mqS = S, *rnqS = S + 32768, *qvS = S + 65536;
    float* mkS = S + 98304, *rnkS = S + 131072, *kvS = S + 163840;

    // 1. weights -> bf16 ; LN(q/k/v) -> stacked bf16 ; zero qg/kg
    wconv<<<dim3(512, 4), 256, 0, stream>>>(Win, Wout, Wup, Wdn,
                                            Winbf, Woutbf, Wupbf, Wdnbf);
    lnconv<<<dim3(1024, 3), 256, 0, stream>>>(q, k, v, g1, b1n, qkvln);
    zero_k<<<4, 256, 0, stream>>>(qg, 1024);

    // 2. stacked projection: fqkv = LN(qkv) @ Win^T  (M=12288)
    mfma_gemm_nt<64, 128, 0, false><<<dim3(4, 192), 256, 0, stream>>>(
        qkvln, Winbf, fq, 12288, 512, 512, nullptr, nullptr);

    // 3. per-(head,row) stats + per-head global means + policy MLP
    head_stats2<<<dim3(4096, 2), 512, 0, stream>>>(fq, fk, S);
    colmean<<<dim3(128, 2), 512, 0, stream>>>(fq, fk, qg, kg);
    policy_mlp<<<8, 64, 0, stream>>>(qg, kg, wpW1, wpb1, wpg, wpb, wpW2, wpb2, wmix);

    // 4. linear-attention K-side reduction (split-8, partials) + reduce + Q-side
    ksideP<<<dim3(32, 8), 256, 0, stream>>>(fk, fv, rnkS, kvS, mkS, Mpart);
    reduceM<<<1040, 256, 0, stream>>>(Mpart, Mbuf);
    qside<<<dim3(16, 32), 256, 0, stream>>>(fq, Mbuf, rnqS, mqS, qvS, wmix, attnbf);

    // 5. q2 = q + attn @ Wout^T + bout  -> d_out
    mfma_gemm_nt<64, 64, 2, false><<<dim3(8, 64), 256, 0, stream>>>(
        attnbf, Woutbf, out, 4096, 512, 512, bout, q);

    // 6. MLP: x2 = LN(q2); h = gelu(x2@Wup^T+bup); out = q2 + h@Wdn^T + bdn
    lnconv<<<dim3(1024, 1), 256, 0, stream>>>(out, out, out, g2, b2n, x2bf);
    mfma_gemm_nt<64, 128, 3, true><<<dim3(16, 64), 256, 0, stream>>>(
        x2bf, Wupbf, hmid, 4096, 2048, 512, bup, nullptr);
    mfma_gemm_nt<64, 128, 2, false><<<dim3(4, 64), 256, 0, stream>>>(
        hmid, Wdnbf, out, 4096, 512, 2048, bdn, out);
}